// Round 5
// baseline (2533.469 us; speedup 1.0000x reference)
//
#include <hip/hip_runtime.h>

// GINE molecule encoder. N=100000, E=1600000, ND=64, ED=16, H=128, L=3, G=1024.
// GEMMs via split-bf16 MFMA (bf16x3): A = Ah+Al, B = Bh+Bl (bf16 planes),
// C ~= Ah*Bh + Ah*Bl + Al*Bh accumulated in fp32 MFMA. ~2^-16 rel error.

#define HCH 128
#define EDIM 16
#define NLAYER 3

typedef __attribute__((ext_vector_type(8))) short  s16x8;
typedef __attribute__((ext_vector_type(4))) float  f32x4;

static __device__ __forceinline__ float4 ld4(const float* p){
  return *reinterpret_cast<const float4*>(p);
}
static __device__ __forceinline__ float2 ld2(const float* p){
  return *reinterpret_cast<const float2*>(p);
}
static __device__ __forceinline__ unsigned short f2bf(float f){
  unsigned u = __float_as_uint(f);
  unsigned r = (u + 0x7FFFu + ((u >> 16) & 1u)) >> 16;
  return (unsigned short)r;
}
static __device__ __forceinline__ float bf2f(unsigned short h){
  return __uint_as_float(((unsigned)h) << 16);
}

// ---------------------------------------------------------------------------
// CSR build
// ---------------------------------------------------------------------------
__global__ void k_hist(const int* __restrict__ dst, int E, int* __restrict__ cnt){
  int j = blockIdx.x*blockDim.x + threadIdx.x;
  if (j < E) atomicAdd(&cnt[dst[j]], 1);
}

#define SC_T 256
#define SC_PER 8
#define SC_CHUNK (SC_T*SC_PER)

__global__ void k_scan1(const int* __restrict__ cnt, int N, int* __restrict__ bsum){
  __shared__ int sh[SC_T];
  int base = blockIdx.x*SC_CHUNK;
  int s = 0;
  #pragma unroll
  for (int u=0;u<SC_PER;++u){ int i = base + threadIdx.x*SC_PER + u; if (i<N) s += cnt[i]; }
  sh[threadIdx.x] = s; __syncthreads();
  for (int off=128; off>0; off>>=1){
    if (threadIdx.x < off) sh[threadIdx.x] += sh[threadIdx.x+off];
    __syncthreads();
  }
  if (threadIdx.x==0) bsum[blockIdx.x] = sh[0];
}

__global__ void k_scan2(const int* __restrict__ bsum, int NB, int* __restrict__ boff,
                        int* __restrict__ row_start, int N){
  if (threadIdx.x==0 && blockIdx.x==0){
    int run = 0;
    for (int b=0;b<NB;++b){ boff[b] = run; run += bsum[b]; }
    row_start[N] = run;
  }
}

__global__ void k_scan3(const int* __restrict__ cnt, int N, const int* __restrict__ boff,
                        int* __restrict__ row_start, int* __restrict__ cursor){
  __shared__ int sh[SC_T];
  int base = blockIdx.x*SC_CHUNK;
  int loc[SC_PER];
  int tsum = 0;
  #pragma unroll
  for (int u=0;u<SC_PER;++u){
    int i = base + threadIdx.x*SC_PER + u;
    int v = (i<N) ? cnt[i] : 0;
    loc[u] = v; tsum += v;
  }
  sh[threadIdx.x] = tsum; __syncthreads();
  for (int off=1; off<SC_T; off<<=1){
    int v = (threadIdx.x>=off) ? sh[threadIdx.x-off] : 0;
    __syncthreads();
    sh[threadIdx.x] += v;
    __syncthreads();
  }
  int run = boff[blockIdx.x] + sh[threadIdx.x] - tsum;
  #pragma unroll
  for (int u=0;u<SC_PER;++u){
    int i = base + threadIdx.x*SC_PER + u;
    if (i<N){ row_start[i] = run; cursor[i] = run; run += loc[u]; }
  }
}

__global__ void k_scatter(const int* __restrict__ src, const int* __restrict__ dst, int E,
                          int* __restrict__ cursor, int* __restrict__ perm,
                          int* __restrict__ src_perm){
  int j = blockIdx.x*blockDim.x + threadIdx.x;
  if (j < E){
    int d = dst[j];
    int pos = atomicAdd(&cursor[d], 1);
    perm[pos] = j;
    src_perm[pos] = src[j];
  }
}

__global__ void k_gather_attr(const int* __restrict__ perm, const float* __restrict__ edge_attr,
                              int E, float* __restrict__ attr_p){
  int t = blockIdx.x*blockDim.x + threadIdx.x;
  int e = t >> 2, f = t & 3;
  if (e < E){
    int j = perm[e];
    float4 v = ld4(edge_attr + (size_t)j*EDIM + f*4);
    *reinterpret_cast<float4*>(attr_p + (size_t)e*EDIM + f*4) = v;
  }
}

// ---------------------------------------------------------------------------
// Message + aggregate (4-edge batched, latency-ordered loads)
// ---------------------------------------------------------------------------
template<bool PRE>
__global__ __launch_bounds__(256) void k_msg(
    const float* __restrict__ h, const float* __restrict__ eattr,
    const int* __restrict__ perm,
    const float* __restrict__ edge_W, const float* __restrict__ edge_b,
    const int* __restrict__ row_start, const int* __restrict__ src_perm,
    int N, float* __restrict__ aggr){
  int wave = threadIdx.x >> 6;
  int lane = threadIdx.x & 63;
  int n = blockIdx.x*4 + wave;
  if (n >= N) return;
  int c = lane*2;
  float w0[EDIM], w1[EDIM];
  #pragma unroll
  for (int k=0;k<EDIM;++k){
    float2 w = ld2(edge_W + k*HCH + c);
    w0[k] = w.x; w1[k] = w.y;
  }
  float2 eb = ld2(edge_b + c);
  const float* hc = h + c;
  float a0 = 0.f, a1 = 0.f;
  int e0 = row_start[n], e1 = row_start[n+1];

  for (int e = e0; e < e1; e += 4){
    int last = e1 - 1;
    int i1 = (e+1 < e1) ? e+1 : last;
    int i2 = (e+2 < e1) ? e+2 : last;
    int i3 = (e+3 < e1) ? e+3 : last;
    int s0 = src_perm[e],  s1 = src_perm[i1];
    int s2 = src_perm[i2], s3 = src_perm[i3];
    const float* ap0; const float* ap1; const float* ap2; const float* ap3;
    if (PRE){
      ap0 = eattr + (size_t)e *EDIM; ap1 = eattr + (size_t)i1*EDIM;
      ap2 = eattr + (size_t)i2*EDIM; ap3 = eattr + (size_t)i3*EDIM;
    } else {
      ap0 = eattr + (size_t)perm[e] *EDIM; ap1 = eattr + (size_t)perm[i1]*EDIM;
      ap2 = eattr + (size_t)perm[i2]*EDIM; ap3 = eattr + (size_t)perm[i3]*EDIM;
    }
    float4 A0 = ld4(ap0), A1 = ld4(ap0+4), A2 = ld4(ap0+8),  A3 = ld4(ap0+12);
    float4 B0 = ld4(ap1), B1 = ld4(ap1+4), B2 = ld4(ap1+8),  B3 = ld4(ap1+12);
    float4 C0 = ld4(ap2), C1 = ld4(ap2+4), C2 = ld4(ap2+8),  C3 = ld4(ap2+12);
    float4 D0 = ld4(ap3), D1 = ld4(ap3+4), D2 = ld4(ap3+8),  D3 = ld4(ap3+12);
    float2 H0 = ld2(hc + (size_t)s0*HCH);
    float2 H1 = ld2(hc + (size_t)s1*HCH);
    float2 H2 = ld2(hc + (size_t)s2*HCH);
    float2 H3 = ld2(hc + (size_t)s3*HCH);
    float av[EDIM] = {A0.x,A0.y,A0.z,A0.w, A1.x,A1.y,A1.z,A1.w,
                      A2.x,A2.y,A2.z,A2.w, A3.x,A3.y,A3.z,A3.w};
    float bv[EDIM] = {B0.x,B0.y,B0.z,B0.w, B1.x,B1.y,B1.z,B1.w,
                      B2.x,B2.y,B2.z,B2.w, B3.x,B3.y,B3.z,B3.w};
    float cv[EDIM] = {C0.x,C0.y,C0.z,C0.w, C1.x,C1.y,C1.z,C1.w,
                      C2.x,C2.y,C2.z,C2.w, C3.x,C3.y,C3.z,C3.w};
    float dv[EDIM] = {D0.x,D0.y,D0.z,D0.w, D1.x,D1.y,D1.z,D1.w,
                      D2.x,D2.y,D2.z,D2.w, D3.x,D3.y,D3.z,D3.w};
    float m0 = eb.x, m1 = eb.y, p0 = eb.x, p1 = eb.y;
    float q0 = eb.x, q1 = eb.y, r0 = eb.x, r1 = eb.y;
    #pragma unroll
    for (int k=0;k<EDIM;++k){
      m0 = fmaf(av[k], w0[k], m0); m1 = fmaf(av[k], w1[k], m1);
      p0 = fmaf(bv[k], w0[k], p0); p1 = fmaf(bv[k], w1[k], p1);
      q0 = fmaf(cv[k], w0[k], q0); q1 = fmaf(cv[k], w1[k], q1);
      r0 = fmaf(dv[k], w0[k], r0); r1 = fmaf(dv[k], w1[k], r1);
    }
    float v1 = (e+1 < e1) ? 1.f : 0.f;
    float v2 = (e+2 < e1) ? 1.f : 0.f;
    float v3 = (e+3 < e1) ? 1.f : 0.f;
    a0 += fmaxf(m0 + H0.x, 0.f);
    a1 += fmaxf(m1 + H0.y, 0.f);
    a0 = fmaf(v1, fmaxf(p0 + H1.x, 0.f), a0);
    a1 = fmaf(v1, fmaxf(p1 + H1.y, 0.f), a1);
    a0 = fmaf(v2, fmaxf(q0 + H2.x, 0.f), a0);
    a1 = fmaf(v2, fmaxf(q1 + H2.y, 0.f), a1);
    a0 = fmaf(v3, fmaxf(r0 + H3.x, 0.f), a0);
    a1 = fmaf(v3, fmaxf(r1 + H3.y, 0.f), a1);
  }
  *reinterpret_cast<float2*>(aggr + (size_t)n*HCH + c) = make_float2(a0, a1);
}

// ---------------------------------------------------------------------------
// Weight prep: W[K][M] fp32 -> Wt hi/lo planes [M][K] bf16 (split precision)
// ---------------------------------------------------------------------------
__global__ void k_prepw(const float* __restrict__ W, int K, int M,
                        unsigned short* __restrict__ hi, unsigned short* __restrict__ lo){
  int t = blockIdx.x*blockDim.x + threadIdx.x;
  if (t < K*M){
    int m = t / K, k = t - m*K;
    float v = W[(size_t)k*M + m];
    unsigned short h = f2bf(v);
    hi[t] = h;
    lo[t] = f2bf(v - bf2f(h));
  }
}

// ---------------------------------------------------------------------------
// Split-bf16 MFMA GEMM: C[nrows,M] = xform(A)[nrows,K] @ W[K,M] + bias
// Tile 128x128, 256 threads (4 waves, each 64x64), BK=64, mfma_f32_16x16x32_bf16.
// LDS planes [128][64] bf16 with XOR swizzle (ushort idx ^= (row&7)<<3) --
// without it this shape is a 16-way bank conflict on ds_read_b128.
// Fragment layouts (verified refs): A: row=l&15, k=(l>>4)*8+j; B(Wt): col=l&15,
// k=(l>>4)*8+j; D: row=(l>>4)*4+reg, col=l&15.
// ---------------------------------------------------------------------------
enum { IN_PLAIN=0, IN_GINE=1, IN_BNRELU=2 };

template<int IN_MODE>
__global__ __launch_bounds__(256, 2) void k_mgemm(
    const float* __restrict__ A, const float* __restrict__ A2,
    const float* __restrict__ epsp,
    const float* __restrict__ bscale, const float* __restrict__ bshift,
    const unsigned short* __restrict__ Wthi, const unsigned short* __restrict__ Wtlo,
    const float* __restrict__ bias, float* __restrict__ C,
    int nrows, int K, int M){
  __shared__ __align__(16) short Zh[128*64];
  __shared__ __align__(16) short Zl[128*64];
  __shared__ __align__(16) short Bh[128*64];
  __shared__ __align__(16) short Bl[128*64];
  int tid = threadIdx.x;
  int rb = blockIdx.x*128, cb = blockIdx.y*128;
  int l = tid & 63, w = tid >> 6;
  int wrow = (w>>1)*64, wcol = (w&1)*64;

  f32x4 acc[4][4];
  #pragma unroll
  for (int fr=0; fr<4; ++fr)
    #pragma unroll
    for (int fc=0; fc<4; ++fc){ f32x4 z = {0.f,0.f,0.f,0.f}; acc[fr][fc] = z; }

  float epsv = 0.f;
  if (IN_MODE==IN_GINE) epsv = 1.0f + *epsp;

  int srow = tid >> 1, shalf = tid & 1;   // staging: 2 threads per row/col

  for (int k0 = 0; k0 < K; k0 += 64){
    // ---- stage Z (fp32 -> hi/lo bf16, with input transform) ----
    {
      bool valid = (rb + srow) < nrows;
      const float* Ar  = A  + (size_t)(rb+srow)*K + k0;
      const float* A2r = (IN_MODE==IN_GINE) ? (A2 + (size_t)(rb+srow)*K + k0) : nullptr;
      #pragma unroll
      for (int s=0; s<4; ++s){
        int ko = (shalf*4 + s)*8;     // 0..56
        float v[8];
        if (valid){
          float4 u0 = ld4(Ar+ko), u1 = ld4(Ar+ko+4);
          v[0]=u0.x; v[1]=u0.y; v[2]=u0.z; v[3]=u0.w;
          v[4]=u1.x; v[5]=u1.y; v[6]=u1.z; v[7]=u1.w;
          if (IN_MODE==IN_GINE){
            float4 a0 = ld4(A2r+ko), a1 = ld4(A2r+ko+4);
            float a[8] = {a0.x,a0.y,a0.z,a0.w,a1.x,a1.y,a1.z,a1.w};
            #pragma unroll
            for (int j=0;j<8;++j) v[j] = fmaf(epsv, v[j], a[j]);
          } else if (IN_MODE==IN_BNRELU){
            float4 sc0 = ld4(bscale + k0+ko), sc1 = ld4(bscale + k0+ko+4);
            float4 sh0 = ld4(bshift + k0+ko), sh1 = ld4(bshift + k0+ko+4);
            float sc[8] = {sc0.x,sc0.y,sc0.z,sc0.w,sc1.x,sc1.y,sc1.z,sc1.w};
            float sh[8] = {sh0.x,sh0.y,sh0.z,sh0.w,sh1.x,sh1.y,sh1.z,sh1.w};
            #pragma unroll
            for (int j=0;j<8;++j) v[j] = fmaxf(fmaf(v[j], sc[j], sh[j]), 0.f);
          }
        } else {
          #pragma unroll
          for (int j=0;j<8;++j) v[j] = 0.f;
        }
        s16x8 hv, lv;
        #pragma unroll
        for (int j=0;j<8;++j){
          unsigned short hb = f2bf(v[j]);
          hv[j] = (short)hb;
          lv[j] = (short)f2bf(v[j] - bf2f(hb));
        }
        int idx = (srow*64 + ko) ^ ((srow&7)<<3);
        *reinterpret_cast<s16x8*>(&Zh[idx]) = hv;
        *reinterpret_cast<s16x8*>(&Zl[idx]) = lv;
      }
    }
    // ---- stage B: Wt hi/lo planes (already bf16) ----
    {
      const unsigned short* Wh = Wthi + (size_t)(cb+srow)*K + k0;
      const unsigned short* Wl = Wtlo + (size_t)(cb+srow)*K + k0;
      #pragma unroll
      for (int s=0; s<4; ++s){
        int ko = (shalf*4 + s)*8;
        s16x8 hv = *reinterpret_cast<const s16x8*>(Wh + ko);
        s16x8 lv = *reinterpret_cast<const s16x8*>(Wl + ko);
        int idx = (srow*64 + ko) ^ ((srow&7)<<3);
        *reinterpret_cast<s16x8*>(&Bh[idx]) = hv;
        *reinterpret_cast<s16x8*>(&Bl[idx]) = lv;
      }
    }
    __syncthreads();
    // ---- compute: 2 k-chunks of 32, 16 frags x 3 mfma each ----
    #pragma unroll
    for (int kc = 0; kc < 64; kc += 32){
      int kgo = kc + (l>>4)*8;
      s16x8 ah[4], al[4], bh[4], bl[4];
      #pragma unroll
      for (int f=0; f<4; ++f){
        int r = wrow + f*16 + (l&15);
        int ia = (r*64 + kgo) ^ ((r&7)<<3);
        ah[f] = *reinterpret_cast<const s16x8*>(&Zh[ia]);
        al[f] = *reinterpret_cast<const s16x8*>(&Zl[ia]);
        int c = wcol + f*16 + (l&15);
        int ib = (c*64 + kgo) ^ ((c&7)<<3);
        bh[f] = *reinterpret_cast<const s16x8*>(&Bh[ib]);
        bl[f] = *reinterpret_cast<const s16x8*>(&Bl[ib]);
      }
      #pragma unroll
      for (int fr=0; fr<4; ++fr)
        #pragma unroll
        for (int fc=0; fc<4; ++fc){
          acc[fr][fc] = __builtin_amdgcn_mfma_f32_16x16x32_bf16(ah[fr], bh[fc], acc[fr][fc], 0,0,0);
          acc[fr][fc] = __builtin_amdgcn_mfma_f32_16x16x32_bf16(ah[fr], bl[fc], acc[fr][fc], 0,0,0);
          acc[fr][fc] = __builtin_amdgcn_mfma_f32_16x16x32_bf16(al[fr], bh[fc], acc[fr][fc], 0,0,0);
        }
    }
    __syncthreads();
  }
  // ---- epilogue: bias add, store ----
  float bv[4];
  #pragma unroll
  for (int fc=0; fc<4; ++fc) bv[fc] = bias[cb + wcol + fc*16 + (l&15)];
  int rbase = rb + wrow + (l>>4)*4;
  #pragma unroll
  for (int fr=0; fr<4; ++fr){
    #pragma unroll
    for (int r=0; r<4; ++r){
      int grow = rbase + fr*16 + r;
      if (grow < nrows){
        float* Cr = C + (size_t)grow*M + cb + wcol + (l&15);
        #pragma unroll
        for (int fc=0; fc<4; ++fc) Cr[fc*16] = acc[fr][fc][r] + bv[fc];
      }
    }
  }
}

// ---------------------------------------------------------------------------
// Column stats pass: sums/sumsq per column of X[nrows][C]  (C divides 256)
// ---------------------------------------------------------------------------
__global__ void k_stats(const float* __restrict__ X, int nrows, int C, int rpb,
                        float* __restrict__ sums, float* __restrict__ sumsq){
  int col = threadIdx.x & (C-1);
  int rstep = 256 / C;
  int r0 = blockIdx.x*rpb + (threadIdx.x >> (C==256 ? 8 : 7));
  int r1 = blockIdx.x*rpb + rpb; if (r1 > nrows) r1 = nrows;
  float s = 0.f, q = 0.f;
  for (int r = r0; r < r1; r += rstep){
    float v = X[(size_t)r*C + col];
    s += v; q = fmaf(v, v, q);
  }
  atomicAdd(&sums[col], s);
  atomicAdd(&sumsq[col], q);
}

// ---------------------------------------------------------------------------
// BN finalize + bn-relu elementwise
// ---------------------------------------------------------------------------
__global__ void k_finalize(const float* __restrict__ sums, const float* __restrict__ sumsq,
                           const float* __restrict__ gamma, const float* __restrict__ beta,
                           float invN, int C, float* __restrict__ scale,
                           float* __restrict__ shift){
  int c = blockIdx.x*blockDim.x + threadIdx.x;
  if (c < C){
    float mu  = sums[c]*invN;
    float var = sumsq[c]*invN - mu*mu;
    float rstd = rsqrtf(var + 1e-5f);
    float sc = gamma[c]*rstd;
    scale[c] = sc;
    shift[c] = beta[c] - mu*sc;
  }
}

__global__ void k_bnrelu(const float* __restrict__ h2, const float* __restrict__ scale,
                         const float* __restrict__ shift, int total4, float* __restrict__ h){
  int i = blockIdx.x*blockDim.x + threadIdx.x;
  if (i < total4){
    int c4 = (i & 31)*4;
    float4 v = reinterpret_cast<const float4*>(h2)[i];
    float4 sc = ld4(scale + c4), sh = ld4(shift + c4);
    v.x = fmaxf(fmaf(v.x, sc.x, sh.x), 0.f);
    v.y = fmaxf(fmaf(v.y, sc.y, sh.y), 0.f);
    v.z = fmaxf(fmaf(v.z, sc.z, sh.z), 0.f);
    v.w = fmaxf(fmaf(v.w, sc.w, sh.w), 0.f);
    reinterpret_cast<float4*>(h)[i] = v;
  }
}

// ---------------------------------------------------------------------------
// Graph boundaries + mean pool
// ---------------------------------------------------------------------------
__global__ void k_bounds(const int* __restrict__ batch, int N,
                         int* __restrict__ gstart, int* __restrict__ gend){
  int n = blockIdx.x*blockDim.x + threadIdx.x;
  if (n < N){
    int b = batch[n];
    if (n == 0) gstart[b] = 0;
    else { int pb = batch[n-1]; if (pb != b){ gstart[b] = n; gend[pb] = n; } }
    if (n == N-1) gend[b] = N;
  }
}

__global__ __launch_bounds__(128) void k_pool(const float* __restrict__ h,
                                              const int* __restrict__ gstart,
                                              const int* __restrict__ gend,
                                              float* __restrict__ pooled){
  int g = blockIdx.x, c = threadIdx.x;
  int s = gstart[g], e = gend[g];
  float acc = 0.f;
  for (int n = s; n < e; ++n) acc += h[(size_t)n*HCH + c];
  pooled[g*HCH + c] = (e > s) ? acc / (float)(e - s) : 0.f;
}

// ---------------------------------------------------------------------------
// Small fp32 GEMM (readout only): 128x128 tile, 8x8/thread
// ---------------------------------------------------------------------------
#define TR 128
#define BKC 64

template<bool OUT_RELU>
__global__ __launch_bounds__(256, 2) void k_gemm(
    const float* __restrict__ A,
    const float* __restrict__ W, const float* __restrict__ bias,
    float* __restrict__ C, int nrows, int K, int M){
  __shared__ __align__(16) float Zl2[TR][BKC+1];
  __shared__ __align__(16) float Wl[BKC][128];
  int tid = threadIdx.x;
  int ty = tid >> 4, tx = tid & 15;
  int rb = blockIdx.x * TR, cb = blockIdx.y * 128;
  float acc[8][8];
  #pragma unroll
  for (int j=0;j<8;++j)
    #pragma unroll
    for (int i=0;i<8;++i) acc[j][i] = 0.f;

  for (int k0 = 0; k0 < K; k0 += BKC){
    #pragma unroll
    for (int t=0;t<8;++t){
      int idx = t*256 + tid;
      int f4 = idx & 15, row = idx >> 4;
      int grow = rb + row, gk = k0 + f4*4;
      float4 v = make_float4(0.f,0.f,0.f,0.f);
      if (grow < nrows) v = ld4(A + (size_t)grow*K + gk);
      Zl2[row][f4*4+0] = v.x; Zl2[row][f4*4+1] = v.y;
      Zl2[row][f4*4+2] = v.z; Zl2[row][f4*4+3] = v.w;
    }
    #pragma unroll
    for (int t=0;t<8;++t){
      int idx = t*256 + tid;
      int f4 = idx & 31, kk = idx >> 5;
      float4 v = ld4(W + (size_t)(k0+kk)*M + cb + f4*4);
      *reinterpret_cast<float4*>(&Wl[kk][f4*4]) = v;
    }
    __syncthreads();
    #pragma unroll 4
    for (int k=0;k<BKC;++k){
      float zr[8], wr[8];
      #pragma unroll
      for (int j=0;j<8;++j) zr[j] = Zl2[ty+16*j][k];
      #pragma unroll
      for (int i=0;i<8;++i) wr[i] = Wl[k][tx+16*i];
      #pragma unroll
      for (int j=0;j<8;++j)
        #pragma unroll
        for (int i=0;i<8;++i) acc[j][i] = fmaf(zr[j], wr[i], acc[j][i]);
    }
    __syncthreads();
  }
  float bv[8];
  #pragma unroll
  for (int i=0;i<8;++i) bv[i] = bias[cb + tx + 16*i];
  #pragma unroll
  for (int j=0;j<8;++j){
    int grow = rb + ty + 16*j;
    if (grow < nrows){
      #pragma unroll
      for (int i=0;i<8;++i){
        float v = acc[j][i] + bv[i];
        if (OUT_RELU) v = fmaxf(v, 0.f);
        C[(size_t)grow*M + cb + tx + 16*i] = v;
      }
    }
  }
}

// ---------------------------------------------------------------------------
extern "C" void kernel_launch(void* const* d_in, const int* in_sizes, int n_in,
                              void* d_out, int out_size, void* d_ws, size_t ws_size,
                              hipStream_t stream){
  const float* x         = (const float*)d_in[0];
  const float* edge_attr = (const float*)d_in[1];
  const int*   edge_index= (const int*)  d_in[2];
  const int*   batch     = (const int*)  d_in[3];
  const float* node_W    = (const float*)d_in[4];
  const float* node_b    = (const float*)d_in[5];
  const float* edge_W    = (const float*)d_in[6];
  const float* edge_b    = (const float*)d_in[7];
  const float* W1s       = (const float*)d_in[8];
  const float* b1s       = (const float*)d_in[9];
  const float* g1s       = (const float*)d_in[10];
  const float* be1s      = (const float*)d_in[11];
  const float* W2s       = (const float*)d_in[12];
  const float* b2s       = (const float*)d_in[13];
  const float* epss      = (const float*)d_in[14];
  const float* bn_g      = (const float*)d_in[15];
  const float* bn_b      = (const float*)d_in[16];
  const float* ro_W1     = (const float*)d_in[17];
  const float* ro_b1     = (const float*)d_in[18];
  const float* ro_W2     = (const float*)d_in[19];
  const float* ro_b2     = (const float*)d_in[20];

  const int N = in_sizes[0] / 64;
  const int E = in_sizes[1] / EDIM;
  const int G = out_size / HCH;
  const int* src = edge_index;
  const int* dst = edge_index + E;

  char* p = (char*)d_ws;
  auto alloc = [&](size_t bytes)->char*{
    char* r = p; p += (bytes + 255) & ~(size_t)255; return r;
  };
  float* h       = (float*)alloc((size_t)N*HCH*4);
  float* aggr    = (float*)alloc((size_t)N*HCH*4);  // aliased as h2 after gemm1
  float* h2      = aggr;
  float* z1      = (float*)alloc((size_t)N*256*4);
  int*   cnt     = (int*)  alloc((size_t)N*4);
  int*   row_start=(int*)  alloc((size_t)(N+1)*4);
  int*   cursor  = (int*)  alloc((size_t)N*4);
  int*   perm    = (int*)  alloc((size_t)E*4);
  int*   src_perm= (int*)  alloc((size_t)E*4);
  int*   bsum    = (int*)  alloc(4096);
  int*   boff    = (int*)  alloc(4096);
  float* sums    = (float*)alloc(256*4);
  float* sumsq   = (float*)alloc(256*4);
  float* scale1  = (float*)alloc(256*4);
  float* shift1  = (float*)alloc(256*4);
  float* scale2  = (float*)alloc(128*4);
  float* shift2  = (float*)alloc(128*4);
  int*   gstart  = (int*)  alloc((size_t)G*4);
  int*   gend    = (int*)  alloc((size_t)G*4);
  float* pooled  = (float*)alloc((size_t)G*HCH*4);
  float* r1      = (float*)alloc((size_t)G*HCH*4);
  // split-bf16 weight planes (Wt: [M][K], hi/lo)
  unsigned short* wtn_hi = (unsigned short*)alloc(128*64*2);
  unsigned short* wtn_lo = (unsigned short*)alloc(128*64*2);
  unsigned short* wt1_hi = (unsigned short*)alloc((size_t)NLAYER*256*128*2);
  unsigned short* wt1_lo = (unsigned short*)alloc((size_t)NLAYER*256*128*2);
  unsigned short* wt2_hi = (unsigned short*)alloc((size_t)NLAYER*128*256*2);
  unsigned short* wt2_lo = (unsigned short*)alloc((size_t)NLAYER*128*256*2);
  // attr_p last: optional if workspace allows (102 MB)
  size_t used = (size_t)(p - (char*)d_ws);
  bool use_pre = (used + (size_t)E*EDIM*4 + 256) <= ws_size;
  float* attr_p  = use_pre ? (float*)alloc((size_t)E*EDIM*4) : nullptr;

  // ---- weight prep (split bf16, transposed) ----
  k_prepw<<<(64*128+255)/256, 256, 0, stream>>>(node_W, 64, 128, wtn_hi, wtn_lo);
  for (int l = 0; l < NLAYER; ++l){
    k_prepw<<<(128*256+255)/256, 256, 0, stream>>>(
        W1s + (size_t)l*128*256, 128, 256, wt1_hi + (size_t)l*32768, wt1_lo + (size_t)l*32768);
    k_prepw<<<(256*128+255)/256, 256, 0, stream>>>(
        W2s + (size_t)l*256*128, 256, 128, wt2_hi + (size_t)l*32768, wt2_lo + (size_t)l*32768);
  }

  // ---- CSR build ----
  hipMemsetAsync(cnt, 0, (size_t)N*4, stream);
  k_hist<<<(E+255)/256, 256, 0, stream>>>(dst, E, cnt);
  int NB = (N + SC_CHUNK - 1)/SC_CHUNK;
  k_scan1<<<NB, SC_T, 0, stream>>>(cnt, N, bsum);
  k_scan2<<<1, 64, 0, stream>>>(bsum, NB, boff, row_start, N);
  k_scan3<<<NB, SC_T, 0, stream>>>(cnt, N, boff, row_start, cursor);
  k_scatter<<<(E+255)/256, 256, 0, stream>>>(src, dst, E, cursor, perm, src_perm);
  if (use_pre)
    k_gather_attr<<<((size_t)E*4+255)/256, 256, 0, stream>>>(perm, edge_attr, E, attr_p);

  // ---- graph boundaries ----
  hipMemsetAsync(gstart, 0, (size_t)G*4, stream);
  hipMemsetAsync(gend,   0, (size_t)G*4, stream);
  k_bounds<<<(N+255)/256, 256, 0, stream>>>(batch, N, gstart, gend);

  const int NRB = (N + 127)/128;
  const float invN = 1.0f/(float)N;
  const int SB = 512;                       // stats blocks
  const int rpb = (N + SB - 1)/SB;

  // ---- node embedding: h = x @ node_W + node_b ----
  k_mgemm<IN_PLAIN><<<dim3(NRB,1), 256, 0, stream>>>(
      x, nullptr, nullptr, nullptr, nullptr, wtn_hi, wtn_lo, node_b, h, N, 64, 128);

  for (int l = 0; l < NLAYER; ++l){
    // aggr = sum relu(h[src] + e)
    if (use_pre)
      k_msg<true><<<(N+3)/4, 256, 0, stream>>>(h, attr_p, nullptr, edge_W, edge_b,
                                               row_start, src_perm, N, aggr);
    else
      k_msg<false><<<(N+3)/4, 256, 0, stream>>>(h, edge_attr, perm, edge_W, edge_b,
                                                row_start, src_perm, N, aggr);
    // z1 = ((1+eps)h + aggr) @ W1 + b1
    k_mgemm<IN_GINE><<<dim3(NRB,2), 256, 0, stream>>>(
        h, aggr, epss + l, nullptr, nullptr,
        wt1_hi + (size_t)l*32768, wt1_lo + (size_t)l*32768,
        b1s + (size_t)l*256, z1, N, 128, 256);
    hipMemsetAsync(sums,  0, 256*4, stream);
    hipMemsetAsync(sumsq, 0, 256*4, stream);
    k_stats<<<SB, 256, 0, stream>>>(z1, N, 256, rpb, sums, sumsq);
    k_finalize<<<1, 256, 0, stream>>>(sums, sumsq, g1s + (size_t)l*256,
                                      be1s + (size_t)l*256, invN, 256, scale1, shift1);
    // h2 = relu(bn(z1)) @ W2 + b2
    k_mgemm<IN_BNRELU><<<dim3(NRB,1), 256, 0, stream>>>(
        z1, nullptr, nullptr, scale1, shift1,
        wt2_hi + (size_t)l*32768, wt2_lo + (size_t)l*32768,
        b2s + (size_t)l*128, h2, N, 256, 128);
    hipMemsetAsync(sums,  0, 128*4, stream);
    hipMemsetAsync(sumsq, 0, 128*4, stream);
    k_stats<<<SB, 256, 0, stream>>>(h2, N, 128, rpb, sums, sumsq);
    k_finalize<<<1, 128, 0, stream>>>(sums, sumsq, bn_g + (size_t)l*128,
                                      bn_b + (size_t)l*128, invN, 128, scale2, shift2);
    // h = relu(bn(h2))
    int total4 = N * (HCH/4);
    k_bnrelu<<<(total4+255)/256, 256, 0, stream>>>(h2, scale2, shift2, total4, h);
  }

  // ---- mean pool + readout ----
  k_pool<<<G, 128, 0, stream>>>(h, gstart, gend, pooled);
  dim3 gr((G + TR - 1)/TR, 1);
  k_gemm<true ><<<gr, 256, 0, stream>>>(pooled, ro_W1, ro_b1, r1, G, 128, 128);
  k_gemm<false><<<gr, 256, 0, stream>>>(r1, ro_W2, ro_b2, (float*)d_out, G, 128, 128);
}

// Round 6
// 1731.189 us; speedup vs baseline: 1.4634x; 1.4634x over previous
//
#include <hip/hip_runtime.h>

// GINE molecule encoder. N=100000, E=1600000, ND=64, ED=16, H=128, L=3, G=1024.
// GEMMs via split-bf16 MFMA (bf16x3). k_msg: cross-batch software pipeline
// (attr via LDS broadcast, H-gathers issued one batch ahead, scalar src loads).

#define HCH 128
#define EDIM 16
#define NLAYER 3

typedef __attribute__((ext_vector_type(8))) short  s16x8;
typedef __attribute__((ext_vector_type(4))) float  f32x4;

static __device__ __forceinline__ float4 ld4(const float* p){
  return *reinterpret_cast<const float4*>(p);
}
static __device__ __forceinline__ float2 ld2(const float* p){
  return *reinterpret_cast<const float2*>(p);
}
static __device__ __forceinline__ unsigned short f2bf(float f){
  unsigned u = __float_as_uint(f);
  unsigned r = (u + 0x7FFFu + ((u >> 16) & 1u)) >> 16;
  return (unsigned short)r;
}
static __device__ __forceinline__ float bf2f(unsigned short h){
  return __uint_as_float(((unsigned)h) << 16);
}

// ---------------------------------------------------------------------------
// CSR build
// ---------------------------------------------------------------------------
__global__ void k_hist(const int* __restrict__ dst, int E, int* __restrict__ cnt){
  int j = blockIdx.x*blockDim.x + threadIdx.x;
  if (j < E) atomicAdd(&cnt[dst[j]], 1);
}

#define SC_T 256
#define SC_PER 8
#define SC_CHUNK (SC_T*SC_PER)

__global__ void k_scan1(const int* __restrict__ cnt, int N, int* __restrict__ bsum){
  __shared__ int sh[SC_T];
  int base = blockIdx.x*SC_CHUNK;
  int s = 0;
  #pragma unroll
  for (int u=0;u<SC_PER;++u){ int i = base + threadIdx.x*SC_PER + u; if (i<N) s += cnt[i]; }
  sh[threadIdx.x] = s; __syncthreads();
  for (int off=128; off>0; off>>=1){
    if (threadIdx.x < off) sh[threadIdx.x] += sh[threadIdx.x+off];
    __syncthreads();
  }
  if (threadIdx.x==0) bsum[blockIdx.x] = sh[0];
}

__global__ void k_scan2(const int* __restrict__ bsum, int NB, int* __restrict__ boff,
                        int* __restrict__ row_start, int N){
  if (threadIdx.x==0 && blockIdx.x==0){
    int run = 0;
    for (int b=0;b<NB;++b){ boff[b] = run; run += bsum[b]; }
    row_start[N] = run;
  }
}

__global__ void k_scan3(const int* __restrict__ cnt, int N, const int* __restrict__ boff,
                        int* __restrict__ row_start, int* __restrict__ cursor){
  __shared__ int sh[SC_T];
  int base = blockIdx.x*SC_CHUNK;
  int loc[SC_PER];
  int tsum = 0;
  #pragma unroll
  for (int u=0;u<SC_PER;++u){
    int i = base + threadIdx.x*SC_PER + u;
    int v = (i<N) ? cnt[i] : 0;
    loc[u] = v; tsum += v;
  }
  sh[threadIdx.x] = tsum; __syncthreads();
  for (int off=1; off<SC_T; off<<=1){
    int v = (threadIdx.x>=off) ? sh[threadIdx.x-off] : 0;
    __syncthreads();
    sh[threadIdx.x] += v;
    __syncthreads();
  }
  int run = boff[blockIdx.x] + sh[threadIdx.x] - tsum;
  #pragma unroll
  for (int u=0;u<SC_PER;++u){
    int i = base + threadIdx.x*SC_PER + u;
    if (i<N){ row_start[i] = run; cursor[i] = run; run += loc[u]; }
  }
}

__global__ void k_scatter(const int* __restrict__ src, const int* __restrict__ dst, int E,
                          int* __restrict__ cursor, int* __restrict__ perm,
                          int* __restrict__ src_perm){
  int j = blockIdx.x*blockDim.x + threadIdx.x;
  if (j < E){
    int d = dst[j];
    int pos = atomicAdd(&cursor[d], 1);
    perm[pos] = j;
    src_perm[pos] = src[j];
  }
}

__global__ void k_gather_attr(const int* __restrict__ perm, const float* __restrict__ edge_attr,
                              int E, float* __restrict__ attr_p){
  int t = blockIdx.x*blockDim.x + threadIdx.x;
  int e = t >> 2, f = t & 3;
  if (e < E){
    int j = perm[e];
    float4 v = ld4(edge_attr + (size_t)j*EDIM + f*4);
    *reinterpret_cast<float4*>(attr_p + (size_t)e*EDIM + f*4) = v;
  }
}

// ---------------------------------------------------------------------------
// k_msg8: pipelined message+aggregate.
// aggr[n] = sum_{e in CSR row n} relu(h[src_e] + attr_e @ edge_W + edge_b)
// One wave per node; lane owns 2 channels. Batches of 8 edges:
//   - srcs loaded 2 batches ahead (wave-uniform -> SGPR)
//   - H gathers issued 1 full batch ahead (~960cy cover vs ~700-900cy latency)
//   - attr: 1 float2/lane/batch, prefetched 1 ahead, staged through LDS,
//     consumed as same-address broadcast float4 reads (conflict-free).
// ---------------------------------------------------------------------------
__global__ __launch_bounds__(256, 4) void k_msg8(
    const float* __restrict__ h, const float* __restrict__ attr_p,
    const float* __restrict__ edge_W, const float* __restrict__ edge_b,
    const int* __restrict__ row_start, const int* __restrict__ src_perm,
    int N, float* __restrict__ aggr){
  __shared__ float attr_lds[4][2][128];   // [wave][dbuf][8 edges x 16 floats]
  int tid = threadIdx.x;
  int wv = __builtin_amdgcn_readfirstlane(tid >> 6);
  int lane = tid & 63;
  int n = blockIdx.x*4 + wv;
  if (n >= N) return;
  int c = lane*2;
  float w0[EDIM], w1[EDIM];
  #pragma unroll
  for (int k=0;k<EDIM;++k){
    float2 w = ld2(edge_W + k*HCH + c);
    w0[k] = w.x; w1[k] = w.y;
  }
  float2 eb = ld2(edge_b + c);
  const float* hc = h + c;
  float a0 = 0.f, a1 = 0.f;
  int e0 = row_start[n], e1 = row_start[n+1];

  if (e0 < e1){
    int last = e1 - 1;
    int nb = (e1 - e0 + 7) >> 3;
    int le = lane >> 3;            // edge-in-batch this lane stages
    int lf = (lane & 7) * 2;       // float offset within attr row
    float* ldsw = &attr_lds[wv][0][0];

    // ---- prologue ----
    int sC[8], sN[8];
    #pragma unroll
    for (int j=0;j<8;++j){ int e=e0+j;   sC[j]=src_perm[e<last?e:last]; }
    #pragma unroll
    for (int j=0;j<8;++j){ int e=e0+8+j; sN[j]=src_perm[e<last?e:last]; }
    float2 HC[8];
    #pragma unroll
    for (int j=0;j<8;++j) HC[j] = ld2(hc + (size_t)sC[j]*HCH);
    int ea = e0 + le; ea = ea<last?ea:last;
    float2 atC = ld2(attr_p + (size_t)ea*EDIM + lf);

    for (int b=0; b<nb; ++b){
      int buf = (b & 1) * 128;
      // 1. publish attr for batch b
      *reinterpret_cast<float2*>(&ldsw[buf + le*16 + lf]) = atC;
      // 2. prefetch attr for b+1
      int ean = e0 + (b+1)*8 + le; ean = ean<last?ean:last;
      float2 atN = ld2(attr_p + (size_t)ean*EDIM + lf);
      // 3. issue H gathers for b+1
      float2 HN[8];
      #pragma unroll
      for (int j=0;j<8;++j) HN[j] = ld2(hc + (size_t)sN[j]*HCH);
      // 4. srcs for b+2
      int sN2[8];
      #pragma unroll
      for (int j=0;j<8;++j){ int e=e0+(b+2)*8+j; sN2[j]=src_perm[e<last?e:last]; }
      // 5. compute batch b
      int vcnt = e1 - (e0 + b*8);
      #pragma unroll
      for (int j=0;j<8;++j){
        const float* ap = &ldsw[buf + j*16];
        float4 t0 = *reinterpret_cast<const float4*>(ap);
        float4 t1 = *reinterpret_cast<const float4*>(ap+4);
        float4 t2 = *reinterpret_cast<const float4*>(ap+8);
        float4 t3 = *reinterpret_cast<const float4*>(ap+12);
        float m0 = eb.x, m1 = eb.y;
        m0 = fmaf(t0.x,w0[0],m0);  m1 = fmaf(t0.x,w1[0],m1);
        m0 = fmaf(t0.y,w0[1],m0);  m1 = fmaf(t0.y,w1[1],m1);
        m0 = fmaf(t0.z,w0[2],m0);  m1 = fmaf(t0.z,w1[2],m1);
        m0 = fmaf(t0.w,w0[3],m0);  m1 = fmaf(t0.w,w1[3],m1);
        m0 = fmaf(t1.x,w0[4],m0);  m1 = fmaf(t1.x,w1[4],m1);
        m0 = fmaf(t1.y,w0[5],m0);  m1 = fmaf(t1.y,w1[5],m1);
        m0 = fmaf(t1.z,w0[6],m0);  m1 = fmaf(t1.z,w1[6],m1);
        m0 = fmaf(t1.w,w0[7],m0);  m1 = fmaf(t1.w,w1[7],m1);
        m0 = fmaf(t2.x,w0[8],m0);  m1 = fmaf(t2.x,w1[8],m1);
        m0 = fmaf(t2.y,w0[9],m0);  m1 = fmaf(t2.y,w1[9],m1);
        m0 = fmaf(t2.z,w0[10],m0); m1 = fmaf(t2.z,w1[10],m1);
        m0 = fmaf(t2.w,w0[11],m0); m1 = fmaf(t2.w,w1[11],m1);
        m0 = fmaf(t3.x,w0[12],m0); m1 = fmaf(t3.x,w1[12],m1);
        m0 = fmaf(t3.y,w0[13],m0); m1 = fmaf(t3.y,w1[13],m1);
        m0 = fmaf(t3.z,w0[14],m0); m1 = fmaf(t3.z,w1[14],m1);
        m0 = fmaf(t3.w,w0[15],m0); m1 = fmaf(t3.w,w1[15],m1);
        float mj = (j < vcnt) ? 1.f : 0.f;
        a0 = fmaf(mj, fmaxf(m0 + HC[j].x, 0.f), a0);
        a1 = fmaf(mj, fmaxf(m1 + HC[j].y, 0.f), a1);
      }
      // 6. rotate pipeline state
      #pragma unroll
      for (int j=0;j<8;++j){ HC[j] = HN[j]; sN[j] = sN2[j]; }
      atC = atN;
    }
  }
  *reinterpret_cast<float2*>(aggr + (size_t)n*HCH + c) = make_float2(a0, a1);
}

// ---------------------------------------------------------------------------
// Weight prep: W[K][M] fp32 -> Wt hi/lo planes [M][K] bf16 (split precision)
// ---------------------------------------------------------------------------
__global__ void k_prepw(const float* __restrict__ W, int K, int M,
                        unsigned short* __restrict__ hi, unsigned short* __restrict__ lo){
  int t = blockIdx.x*blockDim.x + threadIdx.x;
  if (t < K*M){
    int m = t / K, k = t - m*K;
    float v = W[(size_t)k*M + m];
    unsigned short h = f2bf(v);
    hi[t] = h;
    lo[t] = f2bf(v - bf2f(h));
  }
}

// ---------------------------------------------------------------------------
// Split-bf16 MFMA GEMM with optional fused BN column stats.
// Tile 128x128, 4 waves (64x64 each), BK=64, mfma_f32_16x16x32_bf16.
// LDS planes [128][64] bf16, XOR swizzle (ushort idx ^= (row&7)<<3).
// ---------------------------------------------------------------------------
enum { IN_PLAIN=0, IN_GINE=1, IN_BNRELU=2 };

template<int IN_MODE, bool STATS>
__global__ __launch_bounds__(256, 2) void k_mgemm(
    const float* __restrict__ A, const float* __restrict__ A2,
    const float* __restrict__ epsp,
    const float* __restrict__ bscale, const float* __restrict__ bshift,
    const unsigned short* __restrict__ Wthi, const unsigned short* __restrict__ Wtlo,
    const float* __restrict__ bias, float* __restrict__ C,
    float* __restrict__ sums, float* __restrict__ sumsq,
    int nrows, int K, int M){
  __shared__ __align__(16) short Zh[128*64];
  __shared__ __align__(16) short Zl[128*64];
  __shared__ __align__(16) short Bh[128*64];
  __shared__ __align__(16) short Bl[128*64];
  int tid = threadIdx.x;
  int rb = blockIdx.x*128, cb = blockIdx.y*128;
  int l = tid & 63, w = tid >> 6;
  int wrow = (w>>1)*64, wcol = (w&1)*64;

  f32x4 acc[4][4];
  #pragma unroll
  for (int fr=0; fr<4; ++fr)
    #pragma unroll
    for (int fc=0; fc<4; ++fc){ f32x4 z = {0.f,0.f,0.f,0.f}; acc[fr][fc] = z; }

  float epsv = 0.f;
  if (IN_MODE==IN_GINE) epsv = 1.0f + *epsp;

  int srow = tid >> 1, shalf = tid & 1;

  for (int k0 = 0; k0 < K; k0 += 64){
    {
      bool valid = (rb + srow) < nrows;
      const float* Ar  = A  + (size_t)(rb+srow)*K + k0;
      const float* A2r = (IN_MODE==IN_GINE) ? (A2 + (size_t)(rb+srow)*K + k0) : nullptr;
      #pragma unroll
      for (int s=0; s<4; ++s){
        int ko = (shalf*4 + s)*8;
        float v[8];
        if (valid){
          float4 u0 = ld4(Ar+ko), u1 = ld4(Ar+ko+4);
          v[0]=u0.x; v[1]=u0.y; v[2]=u0.z; v[3]=u0.w;
          v[4]=u1.x; v[5]=u1.y; v[6]=u1.z; v[7]=u1.w;
          if (IN_MODE==IN_GINE){
            float4 a0 = ld4(A2r+ko), a1 = ld4(A2r+ko+4);
            float a[8] = {a0.x,a0.y,a0.z,a0.w,a1.x,a1.y,a1.z,a1.w};
            #pragma unroll
            for (int j=0;j<8;++j) v[j] = fmaf(epsv, v[j], a[j]);
          } else if (IN_MODE==IN_BNRELU){
            float4 sc0 = ld4(bscale + k0+ko), sc1 = ld4(bscale + k0+ko+4);
            float4 sh0 = ld4(bshift + k0+ko), sh1 = ld4(bshift + k0+ko+4);
            float sc[8] = {sc0.x,sc0.y,sc0.z,sc0.w,sc1.x,sc1.y,sc1.z,sc1.w};
            float sh[8] = {sh0.x,sh0.y,sh0.z,sh0.w,sh1.x,sh1.y,sh1.z,sh1.w};
            #pragma unroll
            for (int j=0;j<8;++j) v[j] = fmaxf(fmaf(v[j], sc[j], sh[j]), 0.f);
          }
        } else {
          #pragma unroll
          for (int j=0;j<8;++j) v[j] = 0.f;
        }
        s16x8 hv, lv;
        #pragma unroll
        for (int j=0;j<8;++j){
          unsigned short hb = f2bf(v[j]);
          hv[j] = (short)hb;
          lv[j] = (short)f2bf(v[j] - bf2f(hb));
        }
        int idx = (srow*64 + ko) ^ ((srow&7)<<3);
        *reinterpret_cast<s16x8*>(&Zh[idx]) = hv;
        *reinterpret_cast<s16x8*>(&Zl[idx]) = lv;
      }
    }
    {
      const unsigned short* Wh = Wthi + (size_t)(cb+srow)*K + k0;
      const unsigned short* Wl = Wtlo + (size_t)(cb+srow)*K + k0;
      #pragma unroll
      for (int s=0; s<4; ++s){
        int ko = (shalf*4 + s)*8;
        s16x8 hv = *reinterpret_cast<const s16x8*>(Wh + ko);
        s16x8 lv = *reinterpret_cast<const s16x8*>(Wl + ko);
        int idx = (srow*64 + ko) ^ ((srow&7)<<3);
        *reinterpret_cast<s16x8*>(&Bh[idx]) = hv;
        *reinterpret_cast<s16x8*>(&Bl[idx]) = lv;
      }
    }
    __syncthreads();
    #pragma unroll
    for (int kc = 0; kc < 64; kc += 32){
      int kgo = kc + (l>>4)*8;
      s16x8 ah[4], al[4], bh[4], bl[4];
      #pragma unroll
      for (int f=0; f<4; ++f){
        int r = wrow + f*16 + (l&15);
        int ia = (r*64 + kgo) ^ ((r&7)<<3);
        ah[f] = *reinterpret_cast<const s16x8*>(&Zh[ia]);
        al[f] = *reinterpret_cast<const s16x8*>(&Zl[ia]);
        int cc = wcol + f*16 + (l&15);
        int ib = (cc*64 + kgo) ^ ((cc&7)<<3);
        bh[f] = *reinterpret_cast<const s16x8*>(&Bh[ib]);
        bl[f] = *reinterpret_cast<const s16x8*>(&Bl[ib]);
      }
      #pragma unroll
      for (int fr=0; fr<4; ++fr)
        #pragma unroll
        for (int fc=0; fc<4; ++fc){
          acc[fr][fc] = __builtin_amdgcn_mfma_f32_16x16x32_bf16(ah[fr], bh[fc], acc[fr][fc], 0,0,0);
          acc[fr][fc] = __builtin_amdgcn_mfma_f32_16x16x32_bf16(ah[fr], bl[fc], acc[fr][fc], 0,0,0);
          acc[fr][fc] = __builtin_amdgcn_mfma_f32_16x16x32_bf16(al[fr], bh[fc], acc[fr][fc], 0,0,0);
        }
    }
    __syncthreads();
  }
  // ---- epilogue: bias add, store, optional fused stats ----
  float bv[4];
  #pragma unroll
  for (int fc=0; fc<4; ++fc) bv[fc] = bias[cb + wcol + fc*16 + (l&15)];
  float cs[4] = {0.f,0.f,0.f,0.f}, cq[4] = {0.f,0.f,0.f,0.f};
  int rbase = rb + wrow + (l>>4)*4;
  #pragma unroll
  for (int fr=0; fr<4; ++fr){
    #pragma unroll
    for (int r=0; r<4; ++r){
      int grow = rbase + fr*16 + r;
      if (grow < nrows){
        float* Cr = C + (size_t)grow*M + cb + wcol + (l&15);
        #pragma unroll
        for (int fc=0; fc<4; ++fc){
          float v = acc[fr][fc][r] + bv[fc];
          Cr[fc*16] = v;
          if (STATS){ cs[fc] += v; cq[fc] = fmaf(v, v, cq[fc]); }
        }
      }
    }
  }
  if (STATS){
    __syncthreads();
    float* S = reinterpret_cast<float*>(&Zh[0]);   // reuse LDS: 256 floats
    float* Q = S + 128;
    if (tid < 128){ S[tid] = 0.f; Q[tid] = 0.f; }
    __syncthreads();
    #pragma unroll
    for (int fc=0; fc<4; ++fc){
      atomicAdd(&S[wcol + fc*16 + (l&15)], cs[fc]);
      atomicAdd(&Q[wcol + fc*16 + (l&15)], cq[fc]);
    }
    __syncthreads();
    if (tid < 128){
      atomicAdd(&sums[cb + tid], S[tid]);
      atomicAdd(&sumsq[cb + tid], Q[tid]);
    }
  }
}

// ---------------------------------------------------------------------------
// BN finalize + bn-relu elementwise
// ---------------------------------------------------------------------------
__global__ void k_finalize(const float* __restrict__ sums, const float* __restrict__ sumsq,
                           const float* __restrict__ gamma, const float* __restrict__ beta,
                           float invN, int C, float* __restrict__ scale,
                           float* __restrict__ shift){
  int c = blockIdx.x*blockDim.x + threadIdx.x;
  if (c < C){
    float mu  = sums[c]*invN;
    float var = sumsq[c]*invN - mu*mu;
    float rstd = rsqrtf(var + 1e-5f);
    float sc = gamma[c]*rstd;
    scale[c] = sc;
    shift[c] = beta[c] - mu*sc;
  }
}

__global__ void k_bnrelu(const float* __restrict__ h2, const float* __restrict__ scale,
                         const float* __restrict__ shift, int total4, float* __restrict__ h){
  int i = blockIdx.x*blockDim.x + threadIdx.x;
  if (i < total4){
    int c4 = (i & 31)*4;
    float4 v = reinterpret_cast<const float4*>(h2)[i];
    float4 sc = ld4(scale + c4), sh = ld4(shift + c4);
    v.x = fmaxf(fmaf(v.x, sc.x, sh.x), 0.f);
    v.y = fmaxf(fmaf(v.y, sc.y, sh.y), 0.f);
    v.z = fmaxf(fmaf(v.z, sc.z, sh.z), 0.f);
    v.w = fmaxf(fmaf(v.w, sc.w, sh.w), 0.f);
    reinterpret_cast<float4*>(h)[i] = v;
  }
}

// ---------------------------------------------------------------------------
// Graph boundaries + mean pool
// ---------------------------------------------------------------------------
__global__ void k_bounds(const int* __restrict__ batch, int N,
                         int* __restrict__ gstart, int* __restrict__ gend){
  int n = blockIdx.x*blockDim.x + threadIdx.x;
  if (n < N){
    int b = batch[n];
    if (n == 0) gstart[b] = 0;
    else { int pb = batch[n-1]; if (pb != b){ gstart[b] = n; gend[pb] = n; } }
    if (n == N-1) gend[b] = N;
  }
}

__global__ __launch_bounds__(128) void k_pool(const float* __restrict__ h,
                                              const int* __restrict__ gstart,
                                              const int* __restrict__ gend,
                                              float* __restrict__ pooled){
  int g = blockIdx.x, c = threadIdx.x;
  int s = gstart[g], e = gend[g];
  float acc = 0.f;
  for (int n = s; n < e; ++n) acc += h[(size_t)n*HCH + c];
  pooled[g*HCH + c] = (e > s) ? acc / (float)(e - s) : 0.f;
}

// ---------------------------------------------------------------------------
// Small fp32 GEMM (readout only)
// ---------------------------------------------------------------------------
#define TR 128
#define BKC 64

template<bool OUT_RELU>
__global__ __launch_bounds__(256, 2) void k_gemm(
    const float* __restrict__ A,
    const float* __restrict__ W, const float* __restrict__ bias,
    float* __restrict__ C, int nrows, int K, int M){
  __shared__ __align__(16) float Zl2[TR][BKC+1];
  __shared__ __align__(16) float Wl[BKC][128];
  int tid = threadIdx.x;
  int ty = tid >> 4, tx = tid & 15;
  int rb = blockIdx.x * TR, cb = blockIdx.y * 128;
  float acc[8][8];
  #pragma unroll
  for (int j=0;j<8;++j)
    #pragma unroll
    for (int i=0;i<8;++i) acc[j][i] = 0.f;

  for (int k0 = 0; k0 < K; k0 += BKC){
    #pragma unroll
    for (int t=0;t<8;++t){
      int idx = t*256 + tid;
      int f4 = idx & 15, row = idx >> 4;
      int grow = rb + row, gk = k0 + f4*4;
      float4 v = make_float4(0.f,0.f,0.f,0.f);
      if (grow < nrows) v = ld4(A + (size_t)grow*K + gk);
      Zl2[row][f4*4+0] = v.x; Zl2[row][f4*4+1] = v.y;
      Zl2[row][f4*4+2] = v.z; Zl2[row][f4*4+3] = v.w;
    }
    #pragma unroll
    for (int t=0;t<8;++t){
      int idx = t*256 + tid;
      int f4 = idx & 31, kk = idx >> 5;
      float4 v = ld4(W + (size_t)(k0+kk)*M + cb + f4*4);
      *reinterpret_cast<float4*>(&Wl[kk][f4*4]) = v;
    }
    __syncthreads();
    #pragma unroll 4
    for (int k=0;k<BKC;++k){
      float zr[8], wr[8];
      #pragma unroll
      for (int j=0;j<8;++j) zr[j] = Zl2[ty+16*j][k];
      #pragma unroll
      for (int i=0;i<8;++i) wr[i] = Wl[k][tx+16*i];
      #pragma unroll
      for (int j=0;j<8;++j)
        #pragma unroll
        for (int i=0;i<8;++i) acc[j][i] = fmaf(zr[j], wr[i], acc[j][i]);
    }
    __syncthreads();
  }
  float bv[8];
  #pragma unroll
  for (int i=0;i<8;++i) bv[i] = bias[cb + tx + 16*i];
  #pragma unroll
  for (int j=0;j<8;++j){
    int grow = rb + ty + 16*j;
    if (grow < nrows){
      #pragma unroll
      for (int i=0;i<8;++i){
        float v = acc[j][i] + bv[i];
        if (OUT_RELU) v = fmaxf(v, 0.f);
        C[(size_t)grow*M + cb + tx + 16*i] = v;
      }
    }
  }
}

// ---------------------------------------------------------------------------
extern "C" void kernel_launch(void* const* d_in, const int* in_sizes, int n_in,
                              void* d_out, int out_size, void* d_ws, size_t ws_size,
                              hipStream_t stream){
  const float* x         = (const float*)d_in[0];
  const float* edge_attr = (const float*)d_in[1];
  const int*   edge_index= (const int*)  d_in[2];
  const int*   batch     = (const int*)  d_in[3];
  const float* node_W    = (const float*)d_in[4];
  const float* node_b    = (const float*)d_in[5];
  const float* edge_W    = (const float*)d_in[6];
  const float* edge_b    = (const float*)d_in[7];
  const float* W1s       = (const float*)d_in[8];
  const float* b1s       = (const float*)d_in[9];
  const float* g1s       = (const float*)d_in[10];
  const float* be1s      = (const float*)d_in[11];
  const float* W2s       = (const float*)d_in[12];
  const float* b2s       = (const float*)d_in[13];
  const float* epss      = (const float*)d_in[14];
  const float* bn_g      = (const float*)d_in[15];
  const float* bn_b      = (const float*)d_in[16];
  const float* ro_W1     = (const float*)d_in[17];
  const float* ro_b1     = (const float*)d_in[18];
  const float* ro_W2     = (const float*)d_in[19];
  const float* ro_b2     = (const float*)d_in[20];

  const int N = in_sizes[0] / 64;
  const int E = in_sizes[1] / EDIM;
  const int G = out_size / HCH;
  const int* src = edge_index;
  const int* dst = edge_index + E;

  char* p = (char*)d_ws;
  auto alloc = [&](size_t bytes)->char*{
    char* r = p; p += (bytes + 255) & ~(size_t)255; return r;
  };
  float* h       = (float*)alloc((size_t)N*HCH*4);
  float* aggr    = (float*)alloc((size_t)N*HCH*4);  // aliased as h2 after gemm1
  float* h2      = aggr;
  float* z1      = (float*)alloc((size_t)N*256*4);
  int*   cnt     = (int*)  alloc((size_t)N*4);
  int*   row_start=(int*)  alloc((size_t)(N+1)*4);
  int*   cursor  = (int*)  alloc((size_t)N*4);
  int*   perm    = (int*)  alloc((size_t)E*4);
  int*   src_perm= (int*)  alloc((size_t)E*4);
  int*   bsum    = (int*)  alloc(4096);
  int*   boff    = (int*)  alloc(4096);
  float* sums    = (float*)alloc(256*4);
  float* sumsq   = (float*)alloc(256*4);
  float* scale1  = (float*)alloc(256*4);
  float* shift1  = (float*)alloc(256*4);
  float* scale2  = (float*)alloc(128*4);
  float* shift2  = (float*)alloc(128*4);
  int*   gstart  = (int*)  alloc((size_t)G*4);
  int*   gend    = (int*)  alloc((size_t)G*4);
  float* pooled  = (float*)alloc((size_t)G*HCH*4);
  float* r1      = (float*)alloc((size_t)G*HCH*4);
  unsigned short* wtn_hi = (unsigned short*)alloc(128*64*2);
  unsigned short* wtn_lo = (unsigned short*)alloc(128*64*2);
  unsigned short* wt1_hi = (unsigned short*)alloc((size_t)NLAYER*256*128*2);
  unsigned short* wt1_lo = (unsigned short*)alloc((size_t)NLAYER*256*128*2);
  unsigned short* wt2_hi = (unsigned short*)alloc((size_t)NLAYER*128*256*2);
  unsigned short* wt2_lo = (unsigned short*)alloc((size_t)NLAYER*128*256*2);
  size_t used = (size_t)(p - (char*)d_ws);
  bool use_pre = (used + (size_t)E*EDIM*4 + 256) <= ws_size;
  float* attr_p  = use_pre ? (float*)alloc((size_t)E*EDIM*4) : nullptr;

  // ---- weight prep ----
  k_prepw<<<(64*128+255)/256, 256, 0, stream>>>(node_W, 64, 128, wtn_hi, wtn_lo);
  for (int l = 0; l < NLAYER; ++l){
    k_prepw<<<(128*256+255)/256, 256, 0, stream>>>(
        W1s + (size_t)l*128*256, 128, 256, wt1_hi + (size_t)l*32768, wt1_lo + (size_t)l*32768);
    k_prepw<<<(256*128+255)/256, 256, 0, stream>>>(
        W2s + (size_t)l*256*128, 256, 128, wt2_hi + (size_t)l*32768, wt2_lo + (size_t)l*32768);
  }

  // ---- CSR build ----
  hipMemsetAsync(cnt, 0, (size_t)N*4, stream);
  k_hist<<<(E+255)/256, 256, 0, stream>>>(dst, E, cnt);
  int NB = (N + SC_CHUNK - 1)/SC_CHUNK;
  k_scan1<<<NB, SC_T, 0, stream>>>(cnt, N, bsum);
  k_scan2<<<1, 64, 0, stream>>>(bsum, NB, boff, row_start, N);
  k_scan3<<<NB, SC_T, 0, stream>>>(cnt, N, boff, row_start, cursor);
  k_scatter<<<(E+255)/256, 256, 0, stream>>>(src, dst, E, cursor, perm, src_perm);
  if (use_pre)
    k_gather_attr<<<((size_t)E*4+255)/256, 256, 0, stream>>>(perm, edge_attr, E, attr_p);

  // ---- graph boundaries ----
  hipMemsetAsync(gstart, 0, (size_t)G*4, stream);
  hipMemsetAsync(gend,   0, (size_t)G*4, stream);
  k_bounds<<<(N+255)/256, 256, 0, stream>>>(batch, N, gstart, gend);

  const int NRB = (N + 127)/128;
  const float invN = 1.0f/(float)N;

  // ---- node embedding ----
  k_mgemm<IN_PLAIN,false><<<dim3(NRB,1), 256, 0, stream>>>(
      x, nullptr, nullptr, nullptr, nullptr, wtn_hi, wtn_lo, node_b, h,
      nullptr, nullptr, N, 64, 128);

  for (int l = 0; l < NLAYER; ++l){
    // aggr = sum relu(h[src] + e)
    if (use_pre)
      k_msg8<<<(N+3)/4, 256, 0, stream>>>(h, attr_p, edge_W, edge_b,
                                          row_start, src_perm, N, aggr);
    else  // fallback (ws too small): should not happen at this size
      k_msg8<<<(N+3)/4, 256, 0, stream>>>(h, edge_attr, edge_W, edge_b,
                                          row_start, src_perm, N, aggr);
    // z1 = ((1+eps)h + aggr) @ W1 + b1   (stats fused)
    hipMemsetAsync(sums,  0, 256*4, stream);
    hipMemsetAsync(sumsq, 0, 256*4, stream);
    k_mgemm<IN_GINE,true><<<dim3(NRB,2), 256, 0, stream>>>(
        h, aggr, epss + l, nullptr, nullptr,
        wt1_hi + (size_t)l*32768, wt1_lo + (size_t)l*32768,
        b1s + (size_t)l*256, z1, sums, sumsq, N, 128, 256);
    k_finalize<<<1, 256, 0, stream>>>(sums, sumsq, g1s + (size_t)l*256,
                                      be1s + (size_t)l*256, invN, 256, scale1, shift1);
    // h2 = relu(bn(z1)) @ W2 + b2   (stats fused)
    hipMemsetAsync(sums,  0, 128*4, stream);
    hipMemsetAsync(sumsq, 0, 128*4, stream);
    k_mgemm<IN_BNRELU,true><<<dim3(NRB,1), 256, 0, stream>>>(
        z1, nullptr, nullptr, scale1, shift1,
        wt2_hi + (size_t)l*32768, wt2_lo + (size_t)l*32768,
        b2s + (size_t)l*128, h2, sums, sumsq, N, 256, 128);
    k_finalize<<<1, 128, 0, stream>>>(sums, sumsq, bn_g + (size_t)l*128,
                                      bn_b + (size_t)l*128, invN, 128, scale2, shift2);
    // h = relu(bn(h2))
    int total4 = N * (HCH/4);
    k_bnrelu<<<(total4+255)/256, 256, 0, stream>>>(h2, scale2, shift2, total4, h);
  }

  // ---- mean pool + readout ----
  k_pool<<<G, 128, 0, stream>>>(h, gstart, gend, pooled);
  dim3 gr((G + TR - 1)/TR, 1);
  k_gemm<true ><<<gr, 256, 0, stream>>>(pooled, ro_W1, ro_b1, r1, G, 128, 128);
  k_gemm<false><<<gr, 256, 0, stream>>>(r1, ro_W2, ro_b2, (float*)d_out, G, 128, 128);
}

// Round 7
// 1691.022 us; speedup vs baseline: 1.4982x; 1.0238x over previous
//
#include <hip/hip_runtime.h>

// GINE molecule encoder. N=100000, E=1600000, ND=64, ED=16, H=128, L=3, G=1024.
// GEMMs via split-bf16 MFMA (bf16x3). k_msg8: cross-batch pipeline + v_pk_fma_f32
// packed dual-channel edge-dot. BN finalize fused into consumers.

#define HCH 128
#define EDIM 16
#define NLAYER 3

typedef __attribute__((ext_vector_type(8))) short  s16x8;
typedef __attribute__((ext_vector_type(4))) float  f32x4;
typedef __attribute__((ext_vector_type(2))) float  f32x2;

static __device__ __forceinline__ float4 ld4(const float* p){
  return *reinterpret_cast<const float4*>(p);
}
static __device__ __forceinline__ f32x2 ld2v(const float* p){
  return *reinterpret_cast<const f32x2*>(p);
}
static __device__ __forceinline__ unsigned short f2bf(float f){
  unsigned u = __float_as_uint(f);
  unsigned r = (u + 0x7FFFu + ((u >> 16) & 1u)) >> 16;
  return (unsigned short)r;
}
static __device__ __forceinline__ float bf2f(unsigned short h){
  return __uint_as_float(((unsigned)h) << 16);
}

// ---------------------------------------------------------------------------
// CSR build
// ---------------------------------------------------------------------------
__global__ void k_hist(const int* __restrict__ dst, int E, int* __restrict__ cnt){
  int j = blockIdx.x*blockDim.x + threadIdx.x;
  if (j < E) atomicAdd(&cnt[dst[j]], 1);
}

#define SC_T 256
#define SC_PER 8
#define SC_CHUNK (SC_T*SC_PER)

__global__ void k_scan1(const int* __restrict__ cnt, int N, int* __restrict__ bsum){
  __shared__ int sh[SC_T];
  int base = blockIdx.x*SC_CHUNK;
  int s = 0;
  #pragma unroll
  for (int u=0;u<SC_PER;++u){ int i = base + threadIdx.x*SC_PER + u; if (i<N) s += cnt[i]; }
  sh[threadIdx.x] = s; __syncthreads();
  for (int off=128; off>0; off>>=1){
    if (threadIdx.x < off) sh[threadIdx.x] += sh[threadIdx.x+off];
    __syncthreads();
  }
  if (threadIdx.x==0) bsum[blockIdx.x] = sh[0];
}

__global__ void k_scan2(const int* __restrict__ bsum, int NB, int* __restrict__ boff,
                        int* __restrict__ row_start, int N){
  if (threadIdx.x==0 && blockIdx.x==0){
    int run = 0;
    for (int b=0;b<NB;++b){ boff[b] = run; run += bsum[b]; }
    row_start[N] = run;
  }
}

__global__ void k_scan3(const int* __restrict__ cnt, int N, const int* __restrict__ boff,
                        int* __restrict__ row_start, int* __restrict__ cursor){
  __shared__ int sh[SC_T];
  int base = blockIdx.x*SC_CHUNK;
  int loc[SC_PER];
  int tsum = 0;
  #pragma unroll
  for (int u=0;u<SC_PER;++u){
    int i = base + threadIdx.x*SC_PER + u;
    int v = (i<N) ? cnt[i] : 0;
    loc[u] = v; tsum += v;
  }
  sh[threadIdx.x] = tsum; __syncthreads();
  for (int off=1; off<SC_T; off<<=1){
    int v = (threadIdx.x>=off) ? sh[threadIdx.x-off] : 0;
    __syncthreads();
    sh[threadIdx.x] += v;
    __syncthreads();
  }
  int run = boff[blockIdx.x] + sh[threadIdx.x] - tsum;
  #pragma unroll
  for (int u=0;u<SC_PER;++u){
    int i = base + threadIdx.x*SC_PER + u;
    if (i<N){ row_start[i] = run; cursor[i] = run; run += loc[u]; }
  }
}

// Scatter fused with attr gather: one pass, no perm array.
__global__ void k_scatter2(const int* __restrict__ src, const int* __restrict__ dst,
                           const float* __restrict__ edge_attr, int E,
                           int* __restrict__ cursor, int* __restrict__ src_perm,
                           float* __restrict__ attr_p){
  int j = blockIdx.x*blockDim.x + threadIdx.x;
  if (j < E){
    int d = dst[j];
    int pos = atomicAdd(&cursor[d], 1);
    src_perm[pos] = src[j];
    const float* ap = edge_attr + (size_t)j*EDIM;
    float4 a0 = ld4(ap), a1 = ld4(ap+4), a2 = ld4(ap+8), a3 = ld4(ap+12);
    float* op = attr_p + (size_t)pos*EDIM;
    *reinterpret_cast<float4*>(op)    = a0;
    *reinterpret_cast<float4*>(op+4)  = a1;
    *reinterpret_cast<float4*>(op+8)  = a2;
    *reinterpret_cast<float4*>(op+12) = a3;
  }
}

// ---------------------------------------------------------------------------
// k_msg8: pipelined message+aggregate with packed dual-fp32 edge-dot.
// aggr[n] = sum_{e in CSR row n} relu(h[src_e] + attr_e @ edge_W + edge_b)
// One wave per node; lane owns 2 channels (one VGPR pair -> v_pk_fma_f32,
// op_sel broadcasts the shared attr scalar from lo/hi half: 16 pk_fma vs 32 fma).
// ---------------------------------------------------------------------------
__global__ __launch_bounds__(256, 4) void k_msg8(
    const float* __restrict__ h, const float* __restrict__ attr_p,
    const float* __restrict__ edge_W, const float* __restrict__ edge_b,
    const int* __restrict__ row_start, const int* __restrict__ src_perm,
    int N, float* __restrict__ aggr){
  __shared__ float attr_lds[4][2][128];   // [wave][dbuf][8 edges x 16 floats]
  int tid = threadIdx.x;
  int wv = __builtin_amdgcn_readfirstlane(tid >> 6);
  int lane = tid & 63;
  int n = blockIdx.x*4 + wv;
  if (n >= N) return;
  int c = lane*2;
  f32x2 wp[16];
  #pragma unroll
  for (int k=0;k<16;++k) wp[k] = ld2v(edge_W + k*HCH + c);
  f32x2 eb = ld2v(edge_b + c);
  const float* hc = h + c;
  float a0 = 0.f, a1 = 0.f;
  int e0 = row_start[n], e1 = row_start[n+1];

  if (e0 < e1){
    int last = e1 - 1;
    int nb = (e1 - e0 + 7) >> 3;
    int le = lane >> 3;            // edge-in-batch this lane stages
    int lf = (lane & 7) * 2;       // float offset within attr row
    float* ldsw = &attr_lds[wv][0][0];

    // ---- prologue ----
    int sC[8], sN[8];
    #pragma unroll
    for (int j=0;j<8;++j){ int e=e0+j;   sC[j]=src_perm[e<last?e:last]; }
    #pragma unroll
    for (int j=0;j<8;++j){ int e=e0+8+j; sN[j]=src_perm[e<last?e:last]; }
    f32x2 HC[8];
    #pragma unroll
    for (int j=0;j<8;++j) HC[j] = ld2v(hc + (size_t)sC[j]*HCH);
    int ea = e0 + le; ea = ea<last?ea:last;
    f32x2 atC = ld2v(attr_p + (size_t)ea*EDIM + lf);

    for (int b=0; b<nb; ++b){
      int buf = (b & 1) * 128;
      // 1. publish attr for batch b
      *reinterpret_cast<f32x2*>(&ldsw[buf + le*16 + lf]) = atC;
      // 2. prefetch attr for b+1
      int ean = e0 + (b+1)*8 + le; ean = ean<last?ean:last;
      f32x2 atN = ld2v(attr_p + (size_t)ean*EDIM + lf);
      // 3. issue H gathers for b+1
      f32x2 HN[8];
      #pragma unroll
      for (int j=0;j<8;++j) HN[j] = ld2v(hc + (size_t)sN[j]*HCH);
      // 4. srcs for b+2
      int sN2[8];
      #pragma unroll
      for (int j=0;j<8;++j){ int e=e0+(b+2)*8+j; sN2[j]=src_perm[e<last?e:last]; }
      // 5. compute batch b (packed dual-channel dot)
      int vcnt = e1 - (e0 + b*8);
      #pragma unroll
      for (int j=0;j<8;++j){
        const f32x2* ap2 = reinterpret_cast<const f32x2*>(&ldsw[buf + j*16]);
        f32x2 m = eb;
        #pragma unroll
        for (int i=0;i<8;++i){
          f32x2 t = ap2[i];
          // m.lo += wp[2i].lo * t.lo ; m.hi += wp[2i].hi * t.lo
          asm("v_pk_fma_f32 %0, %1, %2, %0 op_sel:[0,0,0] op_sel_hi:[1,0,1]"
              : "+v"(m) : "v"(wp[2*i]), "v"(t));
          // m.lo += wp[2i+1].lo * t.hi ; m.hi += wp[2i+1].hi * t.hi
          asm("v_pk_fma_f32 %0, %1, %2, %0 op_sel:[0,1,0] op_sel_hi:[1,1,1]"
              : "+v"(m) : "v"(wp[2*i+1]), "v"(t));
        }
        float mj = (j < vcnt) ? 1.f : 0.f;
        a0 = fmaf(mj, fmaxf(m[0] + HC[j][0], 0.f), a0);
        a1 = fmaf(mj, fmaxf(m[1] + HC[j][1], 0.f), a1);
      }
      // 6. rotate pipeline state
      #pragma unroll
      for (int j=0;j<8;++j){ HC[j] = HN[j]; sN[j] = sN2[j]; }
      atC = atN;
    }
  }
  *reinterpret_cast<float2*>(aggr + (size_t)n*HCH + c) = make_float2(a0, a1);
}

// ---------------------------------------------------------------------------
// Weight prep, single launch: all 7 matrices -> transposed hi/lo bf16 planes.
// total elems = 64*128 + 3*(128*256) + 3*(256*128) = 204800  (800 blocks x 256)
// ---------------------------------------------------------------------------
__global__ void k_prepall(const float* __restrict__ node_W,
                          const float* __restrict__ W1s, const float* __restrict__ W2s,
                          unsigned short* __restrict__ wtn_hi, unsigned short* __restrict__ wtn_lo,
                          unsigned short* __restrict__ wt1_hi, unsigned short* __restrict__ wt1_lo,
                          unsigned short* __restrict__ wt2_hi, unsigned short* __restrict__ wt2_lo){
  int t = blockIdx.x*blockDim.x + threadIdx.x;
  const float* src; unsigned short *hi, *lo; int K, M, idx;
  if (t < 8192){
    src = node_W; hi = wtn_hi; lo = wtn_lo; K = 64; M = 128; idx = t;
  } else if (t < 8192 + 3*32768){
    int u = t - 8192; int l = u >> 15; idx = u & 32767;
    src = W1s + (size_t)l*32768; hi = wt1_hi + (size_t)l*32768; lo = wt1_lo + (size_t)l*32768;
    K = 128; M = 256;
  } else if (t < 8192 + 6*32768){
    int u = t - 8192 - 3*32768; int l = u >> 15; idx = u & 32767;
    src = W2s + (size_t)l*32768; hi = wt2_hi + (size_t)l*32768; lo = wt2_lo + (size_t)l*32768;
    K = 256; M = 128;
  } else return;
  int m = idx / K, k = idx - m*K;
  float v = src[(size_t)k*M + m];
  unsigned short hb = f2bf(v);
  hi[idx] = hb;
  lo[idx] = f2bf(v - bf2f(hb));
}

// ---------------------------------------------------------------------------
// Split-bf16 MFMA GEMM. Tile 128x128, 4 waves, BK=64, mfma_f32_16x16x32_bf16.
// LDS planes [128][64] bf16, XOR swizzle (ushort idx ^= (row&7)<<3).
// IN_BNRELU computes BN scale/shift from raw sums/sumsq in-kernel (512B LDS
// table per K-step) -- k_finalize eliminated. STATS fuses column sums/sumsq.
// ---------------------------------------------------------------------------
enum { IN_PLAIN=0, IN_GINE=1, IN_BNRELU=2 };

template<int IN_MODE, bool STATS>
__global__ __launch_bounds__(256, 2) void k_mgemm(
    const float* __restrict__ A, const float* __restrict__ A2,
    const float* __restrict__ epsp,
    const float* __restrict__ sums_in, const float* __restrict__ sumsq_in,
    const float* __restrict__ gamma, const float* __restrict__ beta, float invN,
    const unsigned short* __restrict__ Wthi, const unsigned short* __restrict__ Wtlo,
    const float* __restrict__ bias, float* __restrict__ C,
    float* __restrict__ sums_out, float* __restrict__ sumsq_out,
    int nrows, int K, int M){
  __shared__ __align__(16) short Zh[128*64];
  __shared__ __align__(16) short Zl[128*64];
  __shared__ __align__(16) short Bh[128*64];
  __shared__ __align__(16) short Bl[128*64];
  __shared__ float scl[64], shf[64];
  int tid = threadIdx.x;
  int rb = blockIdx.x*128, cb = blockIdx.y*128;
  int l = tid & 63, w = tid >> 6;
  int wrow = (w>>1)*64, wcol = (w&1)*64;

  f32x4 acc[4][4];
  #pragma unroll
  for (int fr=0; fr<4; ++fr)
    #pragma unroll
    for (int fc=0; fc<4; ++fc){ f32x4 z = {0.f,0.f,0.f,0.f}; acc[fr][fc] = z; }

  float epsv = 0.f;
  if (IN_MODE==IN_GINE) epsv = 1.0f + *epsp;

  int srow = tid >> 1, shalf = tid & 1;

  for (int k0 = 0; k0 < K; k0 += 64){
    if (IN_MODE==IN_BNRELU){
      if (tid < 64){
        int kk = k0 + tid;
        float mu  = sums_in[kk]*invN;
        float var = sumsq_in[kk]*invN - mu*mu;
        float rstd = rsqrtf(var + 1e-5f);
        float sc = gamma[kk]*rstd;
        scl[tid] = sc;
        shf[tid] = beta[kk] - mu*sc;
      }
      __syncthreads();
    }
    {
      bool valid = (rb + srow) < nrows;
      const float* Ar  = A  + (size_t)(rb+srow)*K + k0;
      const float* A2r = (IN_MODE==IN_GINE) ? (A2 + (size_t)(rb+srow)*K + k0) : nullptr;
      #pragma unroll
      for (int s=0; s<4; ++s){
        int ko = (shalf*4 + s)*8;
        float v[8];
        if (valid){
          float4 u0 = ld4(Ar+ko), u1 = ld4(Ar+ko+4);
          v[0]=u0.x; v[1]=u0.y; v[2]=u0.z; v[3]=u0.w;
          v[4]=u1.x; v[5]=u1.y; v[6]=u1.z; v[7]=u1.w;
          if (IN_MODE==IN_GINE){
            float4 a0 = ld4(A2r+ko), a1 = ld4(A2r+ko+4);
            float a[8] = {a0.x,a0.y,a0.z,a0.w,a1.x,a1.y,a1.z,a1.w};
            #pragma unroll
            for (int j=0;j<8;++j) v[j] = fmaf(epsv, v[j], a[j]);
          } else if (IN_MODE==IN_BNRELU){
            #pragma unroll
            for (int j=0;j<8;++j) v[j] = fmaxf(fmaf(v[j], scl[ko+j], shf[ko+j]), 0.f);
          }
        } else {
          #pragma unroll
          for (int j=0;j<8;++j) v[j] = 0.f;
        }
        s16x8 hv, lv;
        #pragma unroll
        for (int j=0;j<8;++j){
          unsigned short hb = f2bf(v[j]);
          hv[j] = (short)hb;
          lv[j] = (short)f2bf(v[j] - bf2f(hb));
        }
        int idx = (srow*64 + ko) ^ ((srow&7)<<3);
        *reinterpret_cast<s16x8*>(&Zh[idx]) = hv;
        *reinterpret_cast<s16x8*>(&Zl[idx]) = lv;
      }
    }
    {
      const unsigned short* Wh = Wthi + (size_t)(cb+srow)*K + k0;
      const unsigned short* Wl = Wtlo + (size_t)(cb+srow)*K + k0;
      #pragma unroll
      for (int s=0; s<4; ++s){
        int ko = (shalf*4 + s)*8;
        s16x8 hv = *reinterpret_cast<const s16x8*>(Wh + ko);
        s16x8 lv = *reinterpret_cast<const s16x8*>(Wl + ko);
        int idx = (srow*64 + ko) ^ ((srow&7)<<3);
        *reinterpret_cast<s16x8*>(&Bh[idx]) = hv;
        *reinterpret_cast<s16x8*>(&Bl[idx]) = lv;
      }
    }
    __syncthreads();
    #pragma unroll
    for (int kc = 0; kc < 64; kc += 32){
      int kgo = kc + (l>>4)*8;
      s16x8 ah[4], al[4], bh[4], bl[4];
      #pragma unroll
      for (int f=0; f<4; ++f){
        int r = wrow + f*16 + (l&15);
        int ia = (r*64 + kgo) ^ ((r&7)<<3);
        ah[f] = *reinterpret_cast<const s16x8*>(&Zh[ia]);
        al[f] = *reinterpret_cast<const s16x8*>(&Zl[ia]);
        int cc = wcol + f*16 + (l&15);
        int ib = (cc*64 + kgo) ^ ((cc&7)<<3);
        bh[f] = *reinterpret_cast<const s16x8*>(&Bh[ib]);
        bl[f] = *reinterpret_cast<const s16x8*>(&Bl[ib]);
      }
      #pragma unroll
      for (int fr=0; fr<4; ++fr)
        #pragma unroll
        for (int fc=0; fc<4; ++fc){
          acc[fr][fc] = __builtin_amdgcn_mfma_f32_16x16x32_bf16(ah[fr], bh[fc], acc[fr][fc], 0,0,0);
          acc[fr][fc] = __builtin_amdgcn_mfma_f32_16x16x32_bf16(ah[fr], bl[fc], acc[fr][fc], 0,0,0);
          acc[fr][fc] = __builtin_amdgcn_mfma_f32_16x16x32_bf16(al[fr], bh[fc], acc[fr][fc], 0,0,0);
        }
    }
    __syncthreads();
  }
  // ---- epilogue: bias add, store, optional fused stats ----
  float bv[4];
  #pragma unroll
  for (int fc=0; fc<4; ++fc) bv[fc] = bias[cb + wcol + fc*16 + (l&15)];
  float cs[4] = {0.f,0.f,0.f,0.f}, cq[4] = {0.f,0.f,0.f,0.f};
  int rbase = rb + wrow + (l>>4)*4;
  #pragma unroll
  for (int fr=0; fr<4; ++fr){
    #pragma unroll
    for (int r=0; r<4; ++r){
      int grow = rbase + fr*16 + r;
      if (grow < nrows){
        float* Cr = C + (size_t)grow*M + cb + wcol + (l&15);
        #pragma unroll
        for (int fc=0; fc<4; ++fc){
          float v = acc[fr][fc][r] + bv[fc];
          Cr[fc*16] = v;
          if (STATS){ cs[fc] += v; cq[fc] = fmaf(v, v, cq[fc]); }
        }
      }
    }
  }
  if (STATS){
    __syncthreads();
    float* S = reinterpret_cast<float*>(&Zh[0]);   // reuse LDS: 256 floats
    float* Q = S + 128;
    if (tid < 128){ S[tid] = 0.f; Q[tid] = 0.f; }
    __syncthreads();
    #pragma unroll
    for (int fc=0; fc<4; ++fc){
      atomicAdd(&S[wcol + fc*16 + (l&15)], cs[fc]);
      atomicAdd(&Q[wcol + fc*16 + (l&15)], cq[fc]);
    }
    __syncthreads();
    if (tid < 128){
      atomicAdd(&sums_out[cb + tid], S[tid]);
      atomicAdd(&sumsq_out[cb + tid], Q[tid]);
    }
  }
}

// ---------------------------------------------------------------------------
// bn-relu elementwise with inline finalize (scale/shift from raw sums/sumsq)
// ---------------------------------------------------------------------------
__global__ void k_bnrelu(const float* __restrict__ h2,
                         const float* __restrict__ sums, const float* __restrict__ sumsq,
                         const float* __restrict__ gamma, const float* __restrict__ beta,
                         float invN, int total4, float* __restrict__ h){
  int i = blockIdx.x*blockDim.x + threadIdx.x;
  if (i < total4){
    int c4 = (i & 31)*4;
    float4 v = reinterpret_cast<const float4*>(h2)[i];
    float sc[4], sh[4];
    #pragma unroll
    for (int t=0;t<4;++t){
      int cc = c4 + t;
      float mu  = sums[cc]*invN;
      float var = sumsq[cc]*invN - mu*mu;
      float rstd = rsqrtf(var + 1e-5f);
      float s = gamma[cc]*rstd;
      sc[t] = s; sh[t] = beta[cc] - mu*s;
    }
    v.x = fmaxf(fmaf(v.x, sc[0], sh[0]), 0.f);
    v.y = fmaxf(fmaf(v.y, sc[1], sh[1]), 0.f);
    v.z = fmaxf(fmaf(v.z, sc[2], sh[2]), 0.f);
    v.w = fmaxf(fmaf(v.w, sc[3], sh[3]), 0.f);
    reinterpret_cast<float4*>(h)[i] = v;
  }
}

// ---------------------------------------------------------------------------
// Graph boundaries + mean pool
// ---------------------------------------------------------------------------
__global__ void k_bounds(const int* __restrict__ batch, int N,
                         int* __restrict__ gstart, int* __restrict__ gend){
  int n = blockIdx.x*blockDim.x + threadIdx.x;
  if (n < N){
    int b = batch[n];
    if (n == 0) gstart[b] = 0;
    else { int pb = batch[n-1]; if (pb != b){ gstart[b] = n; gend[pb] = n; } }
    if (n == N-1) gend[b] = N;
  }
}

__global__ __launch_bounds__(128) void k_pool(const float* __restrict__ h,
                                              const int* __restrict__ gstart,
                                              const int* __restrict__ gend,
                                              float* __restrict__ pooled){
  int g = blockIdx.x, c = threadIdx.x;
  int s = gstart[g], e = gend[g];
  float acc = 0.f;
  for (int n = s; n < e; ++n) acc += h[(size_t)n*HCH + c];
  pooled[g*HCH + c] = (e > s) ? acc / (float)(e - s) : 0.f;
}

// ---------------------------------------------------------------------------
// Small fp32 GEMM (readout only)
// ---------------------------------------------------------------------------
#define TR 128
#define BKC 64

template<bool OUT_RELU>
__global__ __launch_bounds__(256, 2) void k_gemm(
    const float* __restrict__ A,
    const float* __restrict__ W, const float* __restrict__ bias,
    float* __restrict__ C, int nrows, int K, int M){
  __shared__ __align__(16) float Zl2[TR][BKC+1];
  __shared__ __align__(16) float Wl[BKC][128];
  int tid = threadIdx.x;
  int ty = tid >> 4, tx = tid & 15;
  int rb = blockIdx.x * TR, cb = blockIdx.y * 128;
  float acc[8][8];
  #pragma unroll
  for (int j=0;j<8;++j)
    #pragma unroll
    for (int i=0;i<8;++i) acc[j][i] = 0.f;

  for (int k0 = 0; k0 < K; k0 += BKC){
    #pragma unroll
    for (int t=0;t<8;++t){
      int idx = t*256 + tid;
      int f4 = idx & 15, row = idx >> 4;
      int grow = rb + row, gk = k0 + f4*4;
      float4 v = make_float4(0.f,0.f,0.f,0.f);
      if (grow < nrows) v = ld4(A + (size_t)grow*K + gk);
      Zl2[row][f4*4+0] = v.x; Zl2[row][f4*4+1] = v.y;
      Zl2[row][f4*4+2] = v.z; Zl2[row][f4*4+3] = v.w;
    }
    #pragma unroll
    for (int t=0;t<8;++t){
      int idx = t*256 + tid;
      int f4 = idx & 31, kk = idx >> 5;
      float4 v = ld4(W + (size_t)(k0+kk)*M + cb + f4*4);
      *reinterpret_cast<float4*>(&Wl[kk][f4*4]) = v;
    }
    __syncthreads();
    #pragma unroll 4
    for (int k=0;k<BKC;++k){
      float zr[8], wr[8];
      #pragma unroll
      for (int j=0;j<8;++j) zr[j] = Zl2[ty+16*j][k];
      #pragma unroll
      for (int i=0;i<8;++i) wr[i] = Wl[k][tx+16*i];
      #pragma unroll
      for (int j=0;j<8;++j)
        #pragma unroll
        for (int i=0;i<8;++i) acc[j][i] = fmaf(zr[j], wr[i], acc[j][i]);
    }
    __syncthreads();
  }
  float bv[8];
  #pragma unroll
  for (int i=0;i<8;++i) bv[i] = bias[cb + tx + 16*i];
  #pragma unroll
  for (int j=0;j<8;++j){
    int grow = rb + ty + 16*j;
    if (grow < nrows){
      #pragma unroll
      for (int i=0;i<8;++i){
        float v = acc[j][i] + bv[i];
        if (OUT_RELU) v = fmaxf(v, 0.f);
        C[(size_t)grow*M + cb + tx + 16*i] = v;
      }
    }
  }
}

// ---------------------------------------------------------------------------
extern "C" void kernel_launch(void* const* d_in, const int* in_sizes, int n_in,
                              void* d_out, int out_size, void* d_ws, size_t ws_size,
                              hipStream_t stream){
  const float* x         = (const float*)d_in[0];
  const float* edge_attr = (const float*)d_in[1];
  const int*   edge_index= (const int*)  d_in[2];
  const int*   batch     = (const int*)  d_in[3];
  const float* node_W    = (const float*)d_in[4];
  const float* node_b    = (const float*)d_in[5];
  const float* edge_W    = (const float*)d_in[6];
  const float* edge_b    = (const float*)d_in[7];
  const float* W1s       = (const float*)d_in[8];
  const float* b1s       = (const float*)d_in[9];
  const float* g1s       = (const float*)d_in[10];
  const float* be1s      = (const float*)d_in[11];
  const float* W2s       = (const float*)d_in[12];
  const float* b2s       = (const float*)d_in[13];
  const float* epss      = (const float*)d_in[14];
  const float* bn_g      = (const float*)d_in[15];
  const float* bn_b      = (const float*)d_in[16];
  const float* ro_W1     = (const float*)d_in[17];
  const float* ro_b1     = (const float*)d_in[18];
  const float* ro_W2     = (const float*)d_in[19];
  const float* ro_b2     = (const float*)d_in[20];

  const int N = in_sizes[0] / 64;
  const int E = in_sizes[1] / EDIM;
  const int G = out_size / HCH;
  const int* src = edge_index;
  const int* dst = edge_index + E;

  char* p = (char*)d_ws;
  auto alloc = [&](size_t bytes)->char*{
    char* r = p; p += (bytes + 255) & ~(size_t)255; return r;
  };
  float* h       = (float*)alloc((size_t)N*HCH*4);
  float* aggr    = (float*)alloc((size_t)N*HCH*4);  // aliased as h2 after gemm1
  float* h2      = aggr;
  float* z1      = (float*)alloc((size_t)N*256*4);
  int*   cnt     = (int*)  alloc((size_t)N*4);
  int*   row_start=(int*)  alloc((size_t)(N+1)*4);
  int*   cursor  = (int*)  alloc((size_t)N*4);
  int*   src_perm= (int*)  alloc((size_t)E*4);
  int*   bsum    = (int*)  alloc(4096);
  int*   boff    = (int*)  alloc(4096);
  float* stat    = (float*)alloc(1024*4);   // statA = stat, statB = stat+512
  float* statA   = stat;
  float* statB   = stat + 512;
  int*   gstart  = (int*)  alloc((size_t)G*4);   // gend contiguous after gstart
  int*   gend    = (int*)  alloc((size_t)G*4);
  float* pooled  = (float*)alloc((size_t)G*HCH*4);
  float* r1      = (float*)alloc((size_t)G*HCH*4);
  unsigned short* wtn_hi = (unsigned short*)alloc(128*64*2);
  unsigned short* wtn_lo = (unsigned short*)alloc(128*64*2);
  unsigned short* wt1_hi = (unsigned short*)alloc((size_t)NLAYER*256*128*2);
  unsigned short* wt1_lo = (unsigned short*)alloc((size_t)NLAYER*256*128*2);
  unsigned short* wt2_hi = (unsigned short*)alloc((size_t)NLAYER*128*256*2);
  unsigned short* wt2_lo = (unsigned short*)alloc((size_t)NLAYER*128*256*2);
  float* attr_p  = (float*)alloc((size_t)E*EDIM*4);

  // ---- weight prep (single launch) ----
  k_prepall<<<800, 256, 0, stream>>>(node_W, W1s, W2s,
                                     wtn_hi, wtn_lo, wt1_hi, wt1_lo, wt2_hi, wt2_lo);

  // ---- CSR build + fused attr permute ----
  hipMemsetAsync(cnt, 0, (size_t)N*4, stream);
  k_hist<<<(E+255)/256, 256, 0, stream>>>(dst, E, cnt);
  int NB = (N + SC_CHUNK - 1)/SC_CHUNK;
  k_scan1<<<NB, SC_T, 0, stream>>>(cnt, N, bsum);
  k_scan2<<<1, 64, 0, stream>>>(bsum, NB, boff, row_start, N);
  k_scan3<<<NB, SC_T, 0, stream>>>(cnt, N, boff, row_start, cursor);
  k_scatter2<<<(E+255)/256, 256, 0, stream>>>(src, dst, edge_attr, E,
                                              cursor, src_perm, attr_p);

  // ---- graph boundaries (gstart+gend zeroed in one memset) ----
  hipMemsetAsync(gstart, 0, (size_t)2*G*4, stream);
  k_bounds<<<(N+255)/256, 256, 0, stream>>>(batch, N, gstart, gend);

  const int NRB = (N + 127)/128;
  const float invN = 1.0f/(float)N;

  // ---- node embedding ----
  k_mgemm<IN_PLAIN,false><<<dim3(NRB,1), 256, 0, stream>>>(
      x, nullptr, nullptr, nullptr, nullptr, nullptr, nullptr, 0.f,
      wtn_hi, wtn_lo, node_b, h, nullptr, nullptr, N, 64, 128);

  for (int l = 0; l < NLAYER; ++l){
    // aggr = sum relu(h[src] + e)
    k_msg8<<<(N+3)/4, 256, 0, stream>>>(h, attr_p, edge_W, edge_b,
                                        row_start, src_perm, N, aggr);
    // zero both stat banks in one memset
    hipMemsetAsync(stat, 0, 1024*4, stream);
    // z1 = ((1+eps)h + aggr) @ W1 + b1   (stats -> statA)
    k_mgemm<IN_GINE,true><<<dim3(NRB,2), 256, 0, stream>>>(
        h, aggr, epss + l, nullptr, nullptr, nullptr, nullptr, invN,
        wt1_hi + (size_t)l*32768, wt1_lo + (size_t)l*32768,
        b1s + (size_t)l*256, z1, statA, statA + 256, N, 128, 256);
    // h2 = relu(bn(z1)) @ W2 + b2   (finalize fused in staging; stats -> statB)
    k_mgemm<IN_BNRELU,true><<<dim3(NRB,1), 256, 0, stream>>>(
        z1, nullptr, nullptr, statA, statA + 256,
        g1s + (size_t)l*256, be1s + (size_t)l*256, invN,
        wt2_hi + (size_t)l*32768, wt2_lo + (size_t)l*32768,
        b2s + (size_t)l*128, h2, statB, statB + 256, N, 256, 128);
    // h = relu(bn(h2))  (finalize fused)
    int total4 = N * (HCH/4);
    k_bnrelu<<<(total4+255)/256, 256, 0, stream>>>(
        h2, statB, statB + 256, bn_g + (size_t)l*128, bn_b + (size_t)l*128,
        invN, total4, h);
  }

  // ---- mean pool + readout ----
  k_pool<<<G, 128, 0, stream>>>(h, gstart, gend, pooled);
  dim3 gr((G + TR - 1)/TR, 1);
  k_gemm<true ><<<gr, 256, 0, stream>>>(pooled, ro_W1, ro_b1, r1, G, 128, 128);
  k_gemm<false><<<gr, 256, 0, stream>>>(r1, ro_W2, ro_b2, (float*)d_out, G, 128, 128);
}